// Round 5
// baseline (318.258 us; speedup 1.0000x reference)
//
#include <hip/hip_runtime.h>
#include <math.h>

// ---------------------------------------------------------------------------
// MultiScaleAdaptiveElasticityLossWithLame
// deformation_field: (2, 3, 160, 192, 160) f32
// image:             (2, 1, 160, 192, 160) f32
// out: scalar f32 = sum over 3 scales of mean(weight * elastic_energy)
// ---------------------------------------------------------------------------

#define LAMBDA_0 1.0f
#define MU_0 1.0f
#define KAPPA_LAMBDA 0.5f
#define KAPPA_MU 0.5f
#define BASE_WEIGHT 1.0f
#define GRADIENT_SCALING 0.1f

typedef float v4f __attribute__((ext_vector_type(4)));

// ------------- scale 0: register-streaming stencil, no LDS, no barriers -----
// Thread owns (1 y-row) x (4 consecutive z); block tile = 32y x 32z; marches
// x over a CX-plane chunk. x+-1 via register plane rotation; y+-1 via loads of
// neighbor rows (L1-resident: same block loads them as centers); z+-1 via the
// 2 scalar halo loads. Latency hidden by per-thread MLP, not barriers.
constexpr int S_TY = 32;
constexpr int S_TZ = 32;
constexpr int S_CX = 8;

struct PR {  // one plane of per-thread registers (56 floats)
    v4f c0, c1, c2, c3;
    v4f ym0, ym1, ym2, ym3;
    v4f yp0, yp1, yp2, yp3;
    float cm0, cm1, cm2, cm3;
    float cp0, cp1, cp2, cp3;
};

#define LOAD_PLANE(P, xq) do {                                                 \
    const long long o_ = (long long)(xq) * sX;                                 \
    P.c0  = *(const v4f*)(p0 + o_ + offC);                                     \
    P.c1  = *(const v4f*)(p1 + o_ + offC);                                     \
    P.c2  = *(const v4f*)(p2 + o_ + offC);                                     \
    P.c3  = *(const v4f*)(p3 + o_ + offC);                                     \
    P.ym0 = *(const v4f*)(p0 + o_ + offYm);                                    \
    P.ym1 = *(const v4f*)(p1 + o_ + offYm);                                    \
    P.ym2 = *(const v4f*)(p2 + o_ + offYm);                                    \
    P.ym3 = *(const v4f*)(p3 + o_ + offYm);                                    \
    P.yp0 = *(const v4f*)(p0 + o_ + offYp);                                    \
    P.yp1 = *(const v4f*)(p1 + o_ + offYp);                                    \
    P.yp2 = *(const v4f*)(p2 + o_ + offYp);                                    \
    P.yp3 = *(const v4f*)(p3 + o_ + offYp);                                    \
    P.cm0 = p0[o_ + offZm]; P.cm1 = p1[o_ + offZm];                            \
    P.cm2 = p2[o_ + offZm]; P.cm3 = p3[o_ + offZm];                            \
    P.cp0 = p0[o_ + offZp]; P.cp1 = p1[o_ + offZp];                            \
    P.cp2 = p2[o_ + offZp]; P.cp3 = p3[o_ + offZp];                            \
} while (0)

__device__ __forceinline__ float plane_energy(
    const PR& P, v4f pc0, v4f pc1, v4f pc2, v4f pc3,
    v4f nc0, v4f nc1, v4f nc2, v4f nc3,
    bool xlo, bool xhi, bool ylo, bool yhi, bool zlo, bool zhi)
{
    v4f gxA[4], gyA[4], gzA[4];
#define FG(ff, cc, ymv, ypv, cmv, cpv, pcv, ncv) {                             \
    v4f c = cc;                                                                \
    gxA[ff] = xlo ? (ncv - c) : (xhi ? (c - pcv) : 0.5f * (ncv - pcv));        \
    gyA[ff] = ylo ? (ypv - c) : (yhi ? (c - ymv) : 0.5f * (ypv - ymv));        \
    v4f gzv;                                                                   \
    gzv[0] = zlo ? (c[1] - c[0]) : 0.5f * (c[1] - cmv);                        \
    gzv[1] = 0.5f * (c[2] - c[0]);                                             \
    gzv[2] = 0.5f * (c[3] - c[1]);                                             \
    gzv[3] = zhi ? (c[3] - c[2]) : 0.5f * (cpv - c[2]);                        \
    gzA[ff] = gzv; }
    FG(0, P.c0, P.ym0, P.yp0, P.cm0, P.cp0, pc0, nc0)
    FG(1, P.c1, P.ym1, P.yp1, P.cm1, P.cp1, pc1, nc1)
    FG(2, P.c2, P.ym2, P.yp2, P.cm2, P.cp2, pc2, nc2)
    FG(3, P.c3, P.ym3, P.yp3, P.cm3, P.cp3, pc3, nc3)
#undef FG
    float s = 0.f;
#pragma unroll
    for (int j = 0; j < 4; ++j) {
        float Exx = gxA[0][j], Eyy = gyA[1][j], Ezz = gzA[2][j];
        float Exy = 0.5f * (gyA[0][j] + gxA[1][j]);
        float Exz = 0.5f * (gzA[0][j] + gxA[2][j]);
        float Eyz = 0.5f * (gzA[1][j] + gyA[2][j]);
        float tr = Exx + Eyy + Ezz;
        float g = sqrtf(gxA[3][j] * gxA[3][j] + gyA[3][j] * gyA[3][j] +
                        gzA[3][j] * gzA[3][j]);
        float lam = LAMBDA_0 + KAPPA_LAMBDA * g;
        float mu  = MU_0 + KAPPA_MU * g;
        float energy = 0.5f * lam * tr * tr +
                       mu * (Exx * Exx + Eyy * Eyy + Ezz * Ezz +
                             2.0f * (Exy * Exy + Exz * Exz + Eyz * Eyz));
        s += (BASE_WEIGHT + GRADIENT_SCALING * g) * energy;
    }
    return s;
}

__global__ void elasticity_stream_reg_kernel(const float* __restrict__ def,
                                             const float* __restrict__ img,
                                             int X, int Y, int Z,
                                             int nby, int nbz, int nbx,
                                             float inv_n,
                                             float* __restrict__ out) {
    int t = blockIdx.x;
    const int bx = t % nbx; t /= nbx;
    const int bz = t % nbz; t /= nbz;
    const int by = t % nby; t /= nby;
    const int b = t;

    const int tid = threadIdx.x;
    const int zg = tid & 7;     // 8 z-groups of 4 -> 32 z
    const int ly = tid >> 3;    // 32 y rows

    const long long vol = (long long)X * Y * Z;
    const long long sX = (long long)Y * Z;
    const float* __restrict__ p0 = def + ((long long)b * 3 + 0) * vol;
    const float* __restrict__ p1 = def + ((long long)b * 3 + 1) * vol;
    const float* __restrict__ p2 = def + ((long long)b * 3 + 2) * vol;
    const float* __restrict__ p3 = img + (long long)b * vol;

    const int gy = by * S_TY + ly;
    const int gz0 = bz * S_TZ + 4 * zg;
    const int x0 = bx * S_CX;

    const long long offC  = (long long)gy * Z + gz0;
    const long long offYm = (long long)max(gy - 1, 0) * Z + gz0;
    const long long offYp = (long long)min(gy + 1, Y - 1) * Z + gz0;
    const long long offZm = offC + ((gz0 > 0) ? -1 : 0);
    const long long offZp = offC + ((gz0 + 4 < Z) ? 4 : 3);

    const bool ylo = (gy == 0), yhi = (gy == Y - 1);
    const bool zlo = (gz0 == 0), zhi = (gz0 + 4 == Z);

    PR A, B2;
    v4f pc0, pc1, pc2, pc3;
    {
        const long long o_ = (long long)max(x0 - 1, 0) * sX;
        pc0 = *(const v4f*)(p0 + o_ + offC);
        pc1 = *(const v4f*)(p1 + o_ + offC);
        pc2 = *(const v4f*)(p2 + o_ + offC);
        pc3 = *(const v4f*)(p3 + o_ + offC);
    }
    LOAD_PLANE(A, x0);

    float acc = 0.f;
#pragma unroll 1
    for (int k = 0; k < S_CX / 2; ++k) {
        const int x = x0 + 2 * k;
        LOAD_PLANE(B2, min(x + 1, X - 1));
        acc += plane_energy(A, pc0, pc1, pc2, pc3,
                            B2.c0, B2.c1, B2.c2, B2.c3,
                            x == 0, x == X - 1, ylo, yhi, zlo, zhi);
        pc0 = A.c0; pc1 = A.c1; pc2 = A.c2; pc3 = A.c3;

        LOAD_PLANE(A, min(x + 2, X - 1));
        acc += plane_energy(B2, pc0, pc1, pc2, pc3,
                            A.c0, A.c1, A.c2, A.c3,
                            false, x + 1 == X - 1, ylo, yhi, zlo, zhi);
        pc0 = B2.c0; pc1 = B2.c1; pc2 = B2.c2; pc3 = B2.c3;
    }

    float val = acc * inv_n;
    for (int off = 32; off > 0; off >>= 1)
        val += __shfl_down(val, off, 64);
    __shared__ float smem[4];
    const int wid = (int)(threadIdx.x >> 6);
    if ((threadIdx.x & 63) == 0) smem[wid] = val;
    __syncthreads();
    if (threadIdx.x == 0) {
        atomicAdd(out, smem[0] + smem[1] + smem[2] + smem[3]);
    }
}

// ------------------- gather kernels (scales 1,2 + downsample) ---------------
// (R3 structure — separate downsample launches; fused z-blocked version
//  regressed coalescing-per-instruction and was reverted.)

__global__ void downsample3d_kernel(const float* __restrict__ in,
                                    float* __restrict__ out,
                                    int nmaps,
                                    int inX, int inY, int inZ,
                                    int outX, int outY, int outZ,
                                    float rx, float ry, float rz) {
    long long total = (long long)nmaps * outX * outY * outZ;
    long long idx = (long long)blockIdx.x * blockDim.x + threadIdx.x;
    if (idx >= total) return;

    int z = (int)(idx % outZ);
    long long t = idx / outZ;
    int y = (int)(t % outY);
    t /= outY;
    int x = (int)(t % outX);
    int m = (int)(t / outX);

    float cx = (float)x * rx;
    float cy = (float)y * ry;
    float cz = (float)z * rz;
    int ix0 = (int)floorf(cx), iy0 = (int)floorf(cy), iz0 = (int)floorf(cz);
    float wx = cx - (float)ix0, wy = cy - (float)iy0, wz = cz - (float)iz0;
    int ix1 = min(ix0 + 1, inX - 1);
    int iy1 = min(iy0 + 1, inY - 1);
    int iz1 = min(iz0 + 1, inZ - 1);

    long long sYZ = (long long)inY * inZ;
    const float* p = in + (long long)m * inX * sYZ;

    long long bx0 = (long long)ix0 * sYZ, bx1 = (long long)ix1 * sYZ;
    long long by0 = (long long)iy0 * inZ, by1 = (long long)iy1 * inZ;

    float v000 = p[bx0 + by0 + iz0], v001 = p[bx0 + by0 + iz1];
    float v010 = p[bx0 + by1 + iz0], v011 = p[bx0 + by1 + iz1];
    float v100 = p[bx1 + by0 + iz0], v101 = p[bx1 + by0 + iz1];
    float v110 = p[bx1 + by1 + iz0], v111 = p[bx1 + by1 + iz1];

    float a00 = v000 * (1.f - wx) + v100 * wx;
    float a01 = v001 * (1.f - wx) + v101 * wx;
    float a10 = v010 * (1.f - wx) + v110 * wx;
    float a11 = v011 * (1.f - wx) + v111 * wx;
    float b0 = a00 * (1.f - wy) + a10 * wy;
    float b1 = a01 * (1.f - wy) + a11 * wy;
    out[idx] = b0 * (1.f - wz) + b1 * wz;
}

__global__ void elasticity_loss_v4_kernel(const float* __restrict__ def,
                                          const float* __restrict__ img,
                                          int B, int X, int Y, int Z,
                                          float inv_n,
                                          float* __restrict__ out) {
    const int Zg = Z >> 2;
    long long total = (long long)B * X * Y * Zg;
    long long idx = (long long)blockIdx.x * blockDim.x + threadIdx.x;
    float val = 0.f;
    if (idx < total) {
        int zg = (int)(idx % Zg);
        long long t = idx / Zg;
        int y = (int)(t % Y);
        t /= Y;
        int x = (int)(t % X);
        int b = (int)(t / X);
        int z0 = zg << 2;

        long long vol = (long long)X * Y * Z;
        const float* base0 = def + ((long long)b * 3 + 0) * vol;
        const float* base1 = def + ((long long)b * 3 + 1) * vol;
        const float* base2 = def + ((long long)b * 3 + 2) * vol;
        const float* base3 = img + (long long)b * vol;
        const float* bases[4] = {base0, base1, base2, base3};

        long long sX = (long long)Y * Z;
        long long c = (long long)x * sX + (long long)y * Z + z0;
        long long cxm = (x > 0) ? c - sX : c;
        long long cxp = (x < X - 1) ? c + sX : c;
        long long cym = (y > 0) ? c - Z : c;
        long long cyp = (y < Y - 1) ? c + Z : c;
        long long czm = (z0 > 0) ? c - 1 : c;
        long long czp = (z0 + 4 < Z) ? c + 4 : c;

        float C[4][4], XM[4][4], XP[4][4], YM[4][4], YP[4][4];
        float ZM[4], ZP[4];
#pragma unroll
        for (int f = 0; f < 4; ++f) {
            const float* p = bases[f];
            float4 tc = *(const float4*)(p + c);
            float4 txm = *(const float4*)(p + cxm);
            float4 txp = *(const float4*)(p + cxp);
            float4 tym = *(const float4*)(p + cym);
            float4 typ = *(const float4*)(p + cyp);
            ZM[f] = p[czm];
            ZP[f] = p[czp];
            C[f][0] = tc.x;  C[f][1] = tc.y;  C[f][2] = tc.z;  C[f][3] = tc.w;
            XM[f][0] = txm.x; XM[f][1] = txm.y; XM[f][2] = txm.z; XM[f][3] = txm.w;
            XP[f][0] = txp.x; XP[f][1] = txp.y; XP[f][2] = txp.z; XP[f][3] = txp.w;
            YM[f][0] = tym.x; YM[f][1] = tym.y; YM[f][2] = tym.z; YM[f][3] = tym.w;
            YP[f][0] = typ.x; YP[f][1] = typ.y; YP[f][2] = typ.z; YP[f][3] = typ.w;
        }

        const bool xlo = (x == 0), xhi = (x == X - 1);
        const bool ylo = (y == 0), yhi = (y == Y - 1);
        const bool zlo = (z0 == 0), zhi = (z0 + 4 == Z);

        float GX[4][4], GY[4][4], GZ[4][4];
#pragma unroll
        for (int f = 0; f < 4; ++f) {
#pragma unroll
            for (int i = 0; i < 4; ++i) {
                GX[f][i] = xlo ? (XP[f][i] - C[f][i])
                               : (xhi ? (C[f][i] - XM[f][i])
                                      : 0.5f * (XP[f][i] - XM[f][i]));
                GY[f][i] = ylo ? (YP[f][i] - C[f][i])
                               : (yhi ? (C[f][i] - YM[f][i])
                                      : 0.5f * (YP[f][i] - YM[f][i]));
            }
            GZ[f][0] = zlo ? (C[f][1] - C[f][0]) : 0.5f * (C[f][1] - ZM[f]);
            GZ[f][1] = 0.5f * (C[f][2] - C[f][0]);
            GZ[f][2] = 0.5f * (C[f][3] - C[f][1]);
            GZ[f][3] = zhi ? (C[f][3] - C[f][2]) : 0.5f * (ZP[f] - C[f][2]);
        }

        float acc = 0.f;
#pragma unroll
        for (int i = 0; i < 4; ++i) {
            float Exx = GX[0][i], Eyy = GY[1][i], Ezz = GZ[2][i];
            float Exy = 0.5f * (GY[0][i] + GX[1][i]);
            float Exz = 0.5f * (GZ[0][i] + GX[2][i]);
            float Eyz = 0.5f * (GZ[1][i] + GY[2][i]);
            float tr = Exx + Eyy + Ezz;
            float g = sqrtf(GX[3][i] * GX[3][i] + GY[3][i] * GY[3][i] +
                            GZ[3][i] * GZ[3][i]);
            float lam = LAMBDA_0 + KAPPA_LAMBDA * g;
            float mu  = MU_0 + KAPPA_MU * g;
            float energy = 0.5f * lam * tr * tr +
                           mu * (Exx * Exx + Eyy * Eyy + Ezz * Ezz +
                                 2.0f * (Exy * Exy + Exz * Exz + Eyz * Eyz));
            float wgt = BASE_WEIGHT + GRADIENT_SCALING * g;
            acc += wgt * energy;
        }
        val = acc * inv_n;
    }

    for (int off = 32; off > 0; off >>= 1)
        val += __shfl_down(val, off, 64);
    __shared__ float smem[8];
    int lane = threadIdx.x & 63;
    int wid = (int)(threadIdx.x >> 6);
    if (lane == 0) smem[wid] = val;
    __syncthreads();
    if (threadIdx.x == 0) {
        float s = 0.f;
        int nw = (int)(blockDim.x >> 6);
        for (int i = 0; i < nw; ++i) s += smem[i];
        atomicAdd(out, s);
    }
}

static void launch_loss_v4(const float* def, const float* img, int B, int X,
                           int Y, int Z, float* out, hipStream_t stream) {
    const int BLOCK = 256;
    long long nvox = (long long)B * X * Y * Z;
    long long total = nvox >> 2;
    float inv_n = (float)(1.0 / (double)nvox);
    int grid = (int)((total + BLOCK - 1) / BLOCK);
    elasticity_loss_v4_kernel<<<grid, BLOCK, 0, stream>>>(def, img, B, X, Y, Z,
                                                          inv_n, out);
}

extern "C" void kernel_launch(void* const* d_in, const int* in_sizes, int n_in,
                              void* d_out, int out_size, void* d_ws, size_t ws_size,
                              hipStream_t stream) {
    const float* def = (const float*)d_in[0];   // (2,3,160,192,160)
    const float* img = (const float*)d_in[1];   // (2,1,160,192,160)
    float* out = (float*)d_out;

    const int B = 2;
    const int X0 = 160, Y0 = 192, Z0 = 160;

    hipMemsetAsync(out, 0, sizeof(float), stream);

    const int BLOCK = 256;

    // ---------------- scale 0: register-streaming stencil ----------------
    {
        long long nvox = (long long)B * X0 * Y0 * Z0;
        float inv_n = (float)(1.0 / (double)nvox);
        int nby = Y0 / S_TY;   // 6
        int nbz = Z0 / S_TZ;   // 5
        int nbx = X0 / S_CX;   // 20
        int grid = B * nby * nbz * nbx;   // 1200
        elasticity_stream_reg_kernel<<<grid, 256, 0, stream>>>(def, img,
                                                               X0, Y0, Z0,
                                                               nby, nbz, nbx,
                                                               inv_n, out);
    }

    // workspace layout
    const int X2 = 80, Y2 = 96, Z2 = 80;
    const int X4 = 40, Y4 = 48, Z4 = 40;
    long long vol2 = (long long)X2 * Y2 * Z2;
    long long vol4 = (long long)X4 * Y4 * Z4;

    float* def2 = (float*)d_ws;
    float* img2 = def2 + (long long)B * 3 * vol2;
    float* def4 = img2 + (long long)B * vol2;
    float* img4 = def4 + (long long)B * 3 * vol4;

    // ---------------- scale 1 (x2 downsample) ----------------
    {
        float rx = (float)((double)(X0 - 1) / (double)(X2 - 1));
        float ry = (float)((double)(Y0 - 1) / (double)(Y2 - 1));
        float rz = (float)((double)(Z0 - 1) / (double)(Z2 - 1));
        long long td = (long long)B * 3 * vol2;
        int gd = (int)((td + BLOCK - 1) / BLOCK);
        downsample3d_kernel<<<gd, BLOCK, 0, stream>>>(def, def2, B * 3,
                                                      X0, Y0, Z0, X2, Y2, Z2,
                                                      rx, ry, rz);
        long long ti = (long long)B * vol2;
        int gi = (int)((ti + BLOCK - 1) / BLOCK);
        downsample3d_kernel<<<gi, BLOCK, 0, stream>>>(img, img2, B,
                                                      X0, Y0, Z0, X2, Y2, Z2,
                                                      rx, ry, rz);
        launch_loss_v4(def2, img2, B, X2, Y2, Z2, out, stream);
    }

    // ---------------- scale 2 (x4 downsample, from original) ----------------
    {
        float rx = (float)((double)(X0 - 1) / (double)(X4 - 1));
        float ry = (float)((double)(Y0 - 1) / (double)(Y4 - 1));
        float rz = (float)((double)(Z0 - 1) / (double)(Z4 - 1));
        long long td = (long long)B * 3 * vol4;
        int gd = (int)((td + BLOCK - 1) / BLOCK);
        downsample3d_kernel<<<gd, BLOCK, 0, stream>>>(def, def4, B * 3,
                                                      X0, Y0, Z0, X4, Y4, Z4,
                                                      rx, ry, rz);
        long long ti = (long long)B * vol4;
        int gi = (int)((ti + BLOCK - 1) / BLOCK);
        downsample3d_kernel<<<gi, BLOCK, 0, stream>>>(img, img4, B,
                                                      X0, Y0, Z0, X4, Y4, Z4,
                                                      rx, ry, rz);
        launch_loss_v4(def4, img4, B, X4, Y4, Z4, out, stream);
    }
}

// Round 6
// 134.821 us; speedup vs baseline: 2.3606x; 2.3606x over previous
//
#include <hip/hip_runtime.h>
#include <math.h>

// ---------------------------------------------------------------------------
// MultiScaleAdaptiveElasticityLossWithLame
// deformation_field: (2, 3, 160, 192, 160) f32
// image:             (2, 1, 160, 192, 160) f32
// out: scalar f32 = sum over 3 scales of mean(weight * elastic_energy)
//
// R6: scale-0 = barrier-free register streamer. Only plane CENTERS persist
// across x (pc/cc/nc ping-pong, 48 VGPR); y+-1 rows loaded per plane and
// folded into GY immediately; z+-1 via lane shuffle (R4-proven) with edge-lane
// scalar loads. __launch_bounds__(256,2) caps VGPR at 128 (R5 spilled at a
// 64-cap with 112 persistent floats -> 409 MB scratch writes).
// ---------------------------------------------------------------------------

#define LAMBDA_0 1.0f
#define MU_0 1.0f
#define KAPPA_LAMBDA 0.5f
#define KAPPA_MU 0.5f
#define BASE_WEIGHT 1.0f
#define GRADIENT_SCALING 0.1f

typedef float v4f __attribute__((ext_vector_type(4)));

constexpr int S_TY = 32;   // y rows per block tile
constexpr int S_TZ = 32;   // z per block tile (8 groups of 4)
constexpr int S_CX = 8;    // x planes per block

__global__ __launch_bounds__(256, 2)
void elasticity_stream_reg2_kernel(const float* __restrict__ def,
                                   const float* __restrict__ img,
                                   int X, int Y, int Z,
                                   int nby, int nbz, int nbx,
                                   float inv_n, float* __restrict__ out) {
    int t = blockIdx.x;
    const int bx = t % nbx; t /= nbx;
    const int bz = t % nbz; t /= nbz;
    const int by = t % nby; t /= nby;
    const int b = t;

    const int tid = threadIdx.x;
    const int zg = tid & 7;     // 8 z-groups of 4 -> 32 z
    const int ly = tid >> 3;    // 32 y rows
    const int lane = tid & 63;
    const int laneM = (lane - 1) & 63;
    const int laneP = (lane + 1) & 63;

    const long long vol = (long long)X * Y * Z;
    const long long sX = (long long)Y * Z;
    const float* __restrict__ p0 = def + ((long long)b * 3 + 0) * vol;
    const float* __restrict__ p1 = def + ((long long)b * 3 + 1) * vol;
    const float* __restrict__ p2 = def + ((long long)b * 3 + 2) * vol;
    const float* __restrict__ p3 = img + (long long)b * vol;

    const int gy = by * S_TY + ly;
    const int gz0 = bz * S_TZ + 4 * zg;
    const int x0 = bx * S_CX;

    const long long offC  = (long long)gy * Z + gz0;
    const long long offYm = (long long)max(gy - 1, 0) * Z + gz0;
    const long long offYp = (long long)min(gy + 1, Y - 1) * Z + gz0;
    const long long offZm = offC - ((gz0 > 0) ? 1 : 0);
    const long long offZp = offC + ((gz0 + 4 < Z) ? 4 : 3);

    const bool ylo = (gy == 0), yhi = (gy == Y - 1);
    const bool zlo = (gz0 == 0), zhi = (gz0 + 4 == Z);
    const bool zem = (zg == 0),  zep = (zg == 7);

    // persistent plane-center state: 3 x 4 fields x float4 = 48 VGPR
    v4f pc[4], cc[4], nc[4];
    {
        const long long o_ = (long long)max(x0 - 1, 0) * sX;
        pc[0] = *(const v4f*)(p0 + o_ + offC);
        pc[1] = *(const v4f*)(p1 + o_ + offC);
        pc[2] = *(const v4f*)(p2 + o_ + offC);
        pc[3] = *(const v4f*)(p3 + o_ + offC);
    }
    {
        const long long o_ = (long long)x0 * sX;
        cc[0] = *(const v4f*)(p0 + o_ + offC);
        cc[1] = *(const v4f*)(p1 + o_ + offC);
        cc[2] = *(const v4f*)(p2 + o_ + offC);
        cc[3] = *(const v4f*)(p3 + o_ + offC);
    }

    float acc = 0.f;
#pragma unroll 2
    for (int i = 0; i < S_CX; ++i) {
        const int x = x0 + i;
        const bool xlo = (x == 0), xhi = (x == X - 1);
        const long long oC = (long long)x * sX;
        const long long oN = (long long)min(x + 1, X - 1) * sX;

        // next-plane centers (needed last -> issued first)
        nc[0] = *(const v4f*)(p0 + oN + offC);
        nc[1] = *(const v4f*)(p1 + oN + offC);
        nc[2] = *(const v4f*)(p2 + oN + offC);
        nc[3] = *(const v4f*)(p3 + oN + offC);

        // current-plane y neighbors (transient; L1/L2 hits of neighbor rows)
        v4f ym[4], yp[4];
        ym[0] = *(const v4f*)(p0 + oC + offYm);
        ym[1] = *(const v4f*)(p1 + oC + offYm);
        ym[2] = *(const v4f*)(p2 + oC + offYm);
        ym[3] = *(const v4f*)(p3 + oC + offYm);
        yp[0] = *(const v4f*)(p0 + oC + offYp);
        yp[1] = *(const v4f*)(p1 + oC + offYp);
        yp[2] = *(const v4f*)(p2 + oC + offYp);
        yp[3] = *(const v4f*)(p3 + oC + offYp);

        // z-halo scalars: only edge lanes of the z-tile load
        float zmS[4] = {0.f, 0.f, 0.f, 0.f};
        float zpS[4] = {0.f, 0.f, 0.f, 0.f};
        if (zem) {
            zmS[0] = p0[oC + offZm]; zmS[1] = p1[oC + offZm];
            zmS[2] = p2[oC + offZm]; zmS[3] = p3[oC + offZm];
        }
        if (zep) {
            zpS[0] = p0[oC + offZp]; zpS[1] = p1[oC + offZp];
            zpS[2] = p2[oC + offZp]; zpS[3] = p3[oC + offZp];
        }

        v4f gxA[4], gyA[4], gzA[4];
#pragma unroll
        for (int f = 0; f < 4; ++f) {
            v4f c = cc[f];
            gxA[f] = xlo ? (nc[f] - c)
                         : (xhi ? (c - pc[f]) : 0.5f * (nc[f] - pc[f]));
            gyA[f] = ylo ? (yp[f] - c)
                         : (yhi ? (c - ym[f]) : 0.5f * (yp[f] - ym[f]));
            // z+-1 from the z-neighbor lane's center registers
            float zmv = __shfl(c[3], laneM, 64);
            float zpv = __shfl(c[0], laneP, 64);
            float zm = zem ? zmS[f] : zmv;
            float zp = zep ? zpS[f] : zpv;
            v4f gz;
            gz[0] = zlo ? (c[1] - c[0]) : 0.5f * (c[1] - zm);
            gz[1] = 0.5f * (c[2] - c[0]);
            gz[2] = 0.5f * (c[3] - c[1]);
            gz[3] = zhi ? (c[3] - c[2]) : 0.5f * (zp - c[2]);
            gzA[f] = gz;
        }

#pragma unroll
        for (int j = 0; j < 4; ++j) {
            float Exx = gxA[0][j], Eyy = gyA[1][j], Ezz = gzA[2][j];
            float Exy = 0.5f * (gyA[0][j] + gxA[1][j]);
            float Exz = 0.5f * (gzA[0][j] + gxA[2][j]);
            float Eyz = 0.5f * (gzA[1][j] + gyA[2][j]);
            float tr = Exx + Eyy + Ezz;
            float g = sqrtf(gxA[3][j] * gxA[3][j] + gyA[3][j] * gyA[3][j] +
                            gzA[3][j] * gzA[3][j]);
            float lam = LAMBDA_0 + KAPPA_LAMBDA * g;
            float mu  = MU_0 + KAPPA_MU * g;
            float energy = 0.5f * lam * tr * tr +
                           mu * (Exx * Exx + Eyy * Eyy + Ezz * Ezz +
                                 2.0f * (Exy * Exy + Exz * Exz + Eyz * Eyz));
            acc += (BASE_WEIGHT + GRADIENT_SCALING * g) * energy;
        }

        // rotate centers
#pragma unroll
        for (int f = 0; f < 4; ++f) { pc[f] = cc[f]; cc[f] = nc[f]; }
    }

    float val = acc * inv_n;
    for (int off = 32; off > 0; off >>= 1)
        val += __shfl_down(val, off, 64);
    __shared__ float smem[4];
    const int wid = (int)(threadIdx.x >> 6);
    if ((threadIdx.x & 63) == 0) smem[wid] = val;
    __syncthreads();
    if (threadIdx.x == 0)
        atomicAdd(out, smem[0] + smem[1] + smem[2] + smem[3]);
}

// ------------------- gather kernels (scales 1,2 + downsample) ---------------
// R3 structure verbatim (best known for the small scales).

__global__ void downsample3d_kernel(const float* __restrict__ in,
                                    float* __restrict__ out,
                                    int nmaps,
                                    int inX, int inY, int inZ,
                                    int outX, int outY, int outZ,
                                    float rx, float ry, float rz) {
    long long total = (long long)nmaps * outX * outY * outZ;
    long long idx = (long long)blockIdx.x * blockDim.x + threadIdx.x;
    if (idx >= total) return;

    int z = (int)(idx % outZ);
    long long t = idx / outZ;
    int y = (int)(t % outY);
    t /= outY;
    int x = (int)(t % outX);
    int m = (int)(t / outX);

    float cx = (float)x * rx;
    float cy = (float)y * ry;
    float cz = (float)z * rz;
    int ix0 = (int)floorf(cx), iy0 = (int)floorf(cy), iz0 = (int)floorf(cz);
    float wx = cx - (float)ix0, wy = cy - (float)iy0, wz = cz - (float)iz0;
    int ix1 = min(ix0 + 1, inX - 1);
    int iy1 = min(iy0 + 1, inY - 1);
    int iz1 = min(iz0 + 1, inZ - 1);

    long long sYZ = (long long)inY * inZ;
    const float* p = in + (long long)m * inX * sYZ;

    long long bx0 = (long long)ix0 * sYZ, bx1 = (long long)ix1 * sYZ;
    long long by0 = (long long)iy0 * inZ, by1 = (long long)iy1 * inZ;

    float v000 = p[bx0 + by0 + iz0], v001 = p[bx0 + by0 + iz1];
    float v010 = p[bx0 + by1 + iz0], v011 = p[bx0 + by1 + iz1];
    float v100 = p[bx1 + by0 + iz0], v101 = p[bx1 + by0 + iz1];
    float v110 = p[bx1 + by1 + iz0], v111 = p[bx1 + by1 + iz1];

    float a00 = v000 * (1.f - wx) + v100 * wx;
    float a01 = v001 * (1.f - wx) + v101 * wx;
    float a10 = v010 * (1.f - wx) + v110 * wx;
    float a11 = v011 * (1.f - wx) + v111 * wx;
    float b0 = a00 * (1.f - wy) + a10 * wy;
    float b1 = a01 * (1.f - wy) + a11 * wy;
    out[idx] = b0 * (1.f - wz) + b1 * wz;
}

__global__ void elasticity_loss_v4_kernel(const float* __restrict__ def,
                                          const float* __restrict__ img,
                                          int B, int X, int Y, int Z,
                                          float inv_n,
                                          float* __restrict__ out) {
    const int Zg = Z >> 2;
    long long total = (long long)B * X * Y * Zg;
    long long idx = (long long)blockIdx.x * blockDim.x + threadIdx.x;
    float val = 0.f;
    if (idx < total) {
        int zg = (int)(idx % Zg);
        long long t = idx / Zg;
        int y = (int)(t % Y);
        t /= Y;
        int x = (int)(t % X);
        int b = (int)(t / X);
        int z0 = zg << 2;

        long long vol = (long long)X * Y * Z;
        const float* base0 = def + ((long long)b * 3 + 0) * vol;
        const float* base1 = def + ((long long)b * 3 + 1) * vol;
        const float* base2 = def + ((long long)b * 3 + 2) * vol;
        const float* base3 = img + (long long)b * vol;
        const float* bases[4] = {base0, base1, base2, base3};

        long long sX = (long long)Y * Z;
        long long c = (long long)x * sX + (long long)y * Z + z0;
        long long cxm = (x > 0) ? c - sX : c;
        long long cxp = (x < X - 1) ? c + sX : c;
        long long cym = (y > 0) ? c - Z : c;
        long long cyp = (y < Y - 1) ? c + Z : c;
        long long czm = (z0 > 0) ? c - 1 : c;
        long long czp = (z0 + 4 < Z) ? c + 4 : c;

        float C[4][4], XM[4][4], XP[4][4], YM[4][4], YP[4][4];
        float ZM[4], ZP[4];
#pragma unroll
        for (int f = 0; f < 4; ++f) {
            const float* p = bases[f];
            float4 tc = *(const float4*)(p + c);
            float4 txm = *(const float4*)(p + cxm);
            float4 txp = *(const float4*)(p + cxp);
            float4 tym = *(const float4*)(p + cym);
            float4 typ = *(const float4*)(p + cyp);
            ZM[f] = p[czm];
            ZP[f] = p[czp];
            C[f][0] = tc.x;  C[f][1] = tc.y;  C[f][2] = tc.z;  C[f][3] = tc.w;
            XM[f][0] = txm.x; XM[f][1] = txm.y; XM[f][2] = txm.z; XM[f][3] = txm.w;
            XP[f][0] = txp.x; XP[f][1] = txp.y; XP[f][2] = txp.z; XP[f][3] = txp.w;
            YM[f][0] = tym.x; YM[f][1] = tym.y; YM[f][2] = tym.z; YM[f][3] = tym.w;
            YP[f][0] = typ.x; YP[f][1] = typ.y; YP[f][2] = typ.z; YP[f][3] = typ.w;
        }

        const bool xlo = (x == 0), xhi = (x == X - 1);
        const bool ylo = (y == 0), yhi = (y == Y - 1);
        const bool zlo = (z0 == 0), zhi = (z0 + 4 == Z);

        float GX[4][4], GY[4][4], GZ[4][4];
#pragma unroll
        for (int f = 0; f < 4; ++f) {
#pragma unroll
            for (int i = 0; i < 4; ++i) {
                GX[f][i] = xlo ? (XP[f][i] - C[f][i])
                               : (xhi ? (C[f][i] - XM[f][i])
                                      : 0.5f * (XP[f][i] - XM[f][i]));
                GY[f][i] = ylo ? (YP[f][i] - C[f][i])
                               : (yhi ? (C[f][i] - YM[f][i])
                                      : 0.5f * (YP[f][i] - YM[f][i]));
            }
            GZ[f][0] = zlo ? (C[f][1] - C[f][0]) : 0.5f * (C[f][1] - ZM[f]);
            GZ[f][1] = 0.5f * (C[f][2] - C[f][0]);
            GZ[f][2] = 0.5f * (C[f][3] - C[f][1]);
            GZ[f][3] = zhi ? (C[f][3] - C[f][2]) : 0.5f * (ZP[f] - C[f][2]);
        }

        float acc = 0.f;
#pragma unroll
        for (int i = 0; i < 4; ++i) {
            float Exx = GX[0][i], Eyy = GY[1][i], Ezz = GZ[2][i];
            float Exy = 0.5f * (GY[0][i] + GX[1][i]);
            float Exz = 0.5f * (GZ[0][i] + GX[2][i]);
            float Eyz = 0.5f * (GZ[1][i] + GY[2][i]);
            float tr = Exx + Eyy + Ezz;
            float g = sqrtf(GX[3][i] * GX[3][i] + GY[3][i] * GY[3][i] +
                            GZ[3][i] * GZ[3][i]);
            float lam = LAMBDA_0 + KAPPA_LAMBDA * g;
            float mu  = MU_0 + KAPPA_MU * g;
            float energy = 0.5f * lam * tr * tr +
                           mu * (Exx * Exx + Eyy * Eyy + Ezz * Ezz +
                                 2.0f * (Exy * Exy + Exz * Exz + Eyz * Eyz));
            float wgt = BASE_WEIGHT + GRADIENT_SCALING * g;
            acc += wgt * energy;
        }
        val = acc * inv_n;
    }

    for (int off = 32; off > 0; off >>= 1)
        val += __shfl_down(val, off, 64);
    __shared__ float smem[8];
    int lane = threadIdx.x & 63;
    int wid = (int)(threadIdx.x >> 6);
    if (lane == 0) smem[wid] = val;
    __syncthreads();
    if (threadIdx.x == 0) {
        float s = 0.f;
        int nw = (int)(blockDim.x >> 6);
        for (int i = 0; i < nw; ++i) s += smem[i];
        atomicAdd(out, s);
    }
}

static void launch_loss_v4(const float* def, const float* img, int B, int X,
                           int Y, int Z, float* out, hipStream_t stream) {
    const int BLOCK = 256;
    long long nvox = (long long)B * X * Y * Z;
    long long total = nvox >> 2;
    float inv_n = (float)(1.0 / (double)nvox);
    int grid = (int)((total + BLOCK - 1) / BLOCK);
    elasticity_loss_v4_kernel<<<grid, BLOCK, 0, stream>>>(def, img, B, X, Y, Z,
                                                          inv_n, out);
}

extern "C" void kernel_launch(void* const* d_in, const int* in_sizes, int n_in,
                              void* d_out, int out_size, void* d_ws, size_t ws_size,
                              hipStream_t stream) {
    const float* def = (const float*)d_in[0];   // (2,3,160,192,160)
    const float* img = (const float*)d_in[1];   // (2,1,160,192,160)
    float* out = (float*)d_out;

    const int B = 2;
    const int X0 = 160, Y0 = 192, Z0 = 160;

    hipMemsetAsync(out, 0, sizeof(float), stream);

    const int BLOCK = 256;

    // ---------------- scale 0: register streamer ----------------
    {
        long long nvox = (long long)B * X0 * Y0 * Z0;
        float inv_n = (float)(1.0 / (double)nvox);
        int nby = Y0 / S_TY;   // 6
        int nbz = Z0 / S_TZ;   // 5
        int nbx = X0 / S_CX;   // 20
        int grid = B * nby * nbz * nbx;   // 1200
        elasticity_stream_reg2_kernel<<<grid, 256, 0, stream>>>(def, img,
                                                                X0, Y0, Z0,
                                                                nby, nbz, nbx,
                                                                inv_n, out);
    }

    // workspace layout
    const int X2 = 80, Y2 = 96, Z2 = 80;
    const int X4 = 40, Y4 = 48, Z4 = 40;
    long long vol2 = (long long)X2 * Y2 * Z2;
    long long vol4 = (long long)X4 * Y4 * Z4;

    float* def2 = (float*)d_ws;
    float* img2 = def2 + (long long)B * 3 * vol2;
    float* def4 = img2 + (long long)B * vol2;
    float* img4 = def4 + (long long)B * 3 * vol4;

    // ---------------- scale 1 (x2 downsample) ----------------
    {
        float rx = (float)((double)(X0 - 1) / (double)(X2 - 1));
        float ry = (float)((double)(Y0 - 1) / (double)(Y2 - 1));
        float rz = (float)((double)(Z0 - 1) / (double)(Z2 - 1));
        long long td = (long long)B * 3 * vol2;
        int gd = (int)((td + BLOCK - 1) / BLOCK);
        downsample3d_kernel<<<gd, BLOCK, 0, stream>>>(def, def2, B * 3,
                                                      X0, Y0, Z0, X2, Y2, Z2,
                                                      rx, ry, rz);
        long long ti = (long long)B * vol2;
        int gi = (int)((ti + BLOCK - 1) / BLOCK);
        downsample3d_kernel<<<gi, BLOCK, 0, stream>>>(img, img2, B,
                                                      X0, Y0, Z0, X2, Y2, Z2,
                                                      rx, ry, rz);
        launch_loss_v4(def2, img2, B, X2, Y2, Z2, out, stream);
    }

    // ---------------- scale 2 (x4 downsample, from original) ----------------
    {
        float rx = (float)((double)(X0 - 1) / (double)(X4 - 1));
        float ry = (float)((double)(Y0 - 1) / (double)(Y4 - 1));
        float rz = (float)((double)(Z0 - 1) / (double)(Z4 - 1));
        long long td = (long long)B * 3 * vol4;
        int gd = (int)((td + BLOCK - 1) / BLOCK);
        downsample3d_kernel<<<gd, BLOCK, 0, stream>>>(def, def4, B * 3,
                                                      X0, Y0, Z0, X4, Y4, Z4,
                                                      rx, ry, rz);
        long long ti = (long long)B * vol4;
        int gi = (int)((ti + BLOCK - 1) / BLOCK);
        downsample3d_kernel<<<gi, BLOCK, 0, stream>>>(img, img4, B,
                                                      X0, Y0, Z0, X4, Y4, Z4,
                                                      rx, ry, rz);
        launch_loss_v4(def4, img4, B, X4, Y4, Z4, out, stream);
    }
}